// Round 3
// baseline (181.068 us; speedup 1.0000x reference)
//
#include <hip/hip_runtime.h>

// B=16 images, A=65536 anchors, G=32 gts. Inputs float32; output slot read as
// bf16 low-16-bits (R4/R5: dual-encode store gives absmax 0.0 -> keep it).
#define BB 16
#define AA 65536
#define GG 32
// Histogram: key = (float_bits>>14) - KOFF, bin 0 == 2^-10, 512 bins/octave.
// Count-only, value = bin midpoint (rel err <= 2^-10 << 2% budget; R5 absmax 0.0).
#define NB 8192
#define KOFF 59904u          // __float_as_uint(2^-10) >> 14
#define AT 4                 // anchors per thread in k_matchforce
#define APB (256 * AT)       // 1024 anchors per block
#define MBLK (AA / APB)      // 64 match blocks per image
#define NSEG 16              // stats segments per image
#define SEGA (AA / NSEG)     // 4096 anchors per stats block

// All scratch in device globals; every buffer is FULLY rewritten each call
// (no zero-init kernel, no global atomics, no d_ws use, re-poison safe).
__device__ unsigned char      g_mask[(size_t)BB * AA];
__device__ unsigned char      g_bidx[(size_t)BB * AA];
__device__ unsigned long long g_fpart[(size_t)BB * GG * MBLK];
__device__ unsigned int       g_hpart[(size_t)BB * NSEG * (NB/2)]; // 4 MB packed
__device__ float g_spart[BB * NSEG * 2];   // pos, loc partials
__device__ int   g_npart[BB * NSEG];
__device__ float g_loc[BB], g_pos[BB], g_neg[BB];
__device__ int   g_npos[BB], g_nneg[BB];

__device__ __forceinline__ float midval(int bin) {
    return __uint_as_float((((unsigned int)bin + KOFF) << 14) | 8192u);
}

// ---------------------------------------------------------------------------
// Kernel 1: fused per-anchor match + per-gt force-match partials.
// grid (MBLK, B), block 256, AT=4 anchors/thread (strided, coalesced).
// Divide-free scoring: r = inter/(areaA+areaG) is a monotone transform of IoU
// (iou = r/(1-r)), so argmax over r == argmax over iou, and iou>0.5 <=> r>1/3
// (rcp 1-ulp error absorbed by bf16 budget; verified absmax 0.0 in R2 bench).
// Force match (NO per-thread GG arrays -- R2 post-mortem: fl[32]/fid[32] went
// to scratch, VGPR=40, 3x instr bloat): each gt handled entirely inside its
// unrolled iteration. Thread reduces its 4 candidates to named scalars, then
// guarded 64-bit LDS atomicMax on key = (r_bits<<32)|(~offset); tie-break =
// lowest anchor offset. Guard reads hi/lo as two 32-bit LDS reads (tear-free);
// key is monotone under atomicMax, so stale guard reads only cause harmless
// extra atomics, never a wrong skip. Init key = (r=0, offset 0): the r==0
// masses fail the guard -> no same-address atomic flood.
__global__ void __launch_bounds__(256, 4)
k_matchforce(const float4* __restrict__ anchors,
             const float4* __restrict__ gts) {
    __shared__ float4 sg[GG];
    __shared__ float sga[GG];
    __shared__ unsigned long long vkey[GG];
    const int b = blockIdx.y;
    const int t = threadIdx.x;
    if (t < GG) {
        const float4 g4 = gts[(size_t)b * GG + t];
        sg[t] = g4;
        sga[t] = (g4.z - g4.x) * (g4.w - g4.y);
        vkey[t] = 0xFFFFFFFFull;          // r=0, block-local offset 0
    }
    __syncthreads();

    const size_t abase = (size_t)b * AA + (size_t)blockIdx.x * APB;

    float ax0[AT], ay0[AT], ax1[AT], ay1[AT], aar[AT], best[AT];
    int bg[AT];
#pragma unroll
    for (int j = 0; j < AT; ++j) {
        const float4 av = anchors[abase + j * 256 + t];
        ax0[j] = av.x; ay0[j] = av.y; ax1[j] = av.z; ay1[j] = av.w;
        aar[j] = (av.z - av.x) * (av.w - av.y);
        best[j] = -1.0f; bg[j] = 0;
    }

#pragma unroll
    for (int g = 0; g < GG; ++g) {
        const float4 gb = sg[g];
        const float ga = sga[g];
        float fbest = -1.0f;              // r >= 0 always -> j=0 wins init
        int fo = t;                       // block-local offset of j=0 anchor
#pragma unroll
        for (int j = 0; j < AT; ++j) {
            const float lx = fmaxf(ax0[j], gb.x), ly = fmaxf(ay0[j], gb.y);
            const float rx = fminf(ax1[j], gb.z), ry = fminf(ay1[j], gb.w);
            const float w = fmaxf(rx - lx, 0.0f), h = fmaxf(ry - ly, 0.0f);
            const float inter = w * h;
            const float s = aar[j] + ga;                    // areaA + areaG > 0
            const float r = inter * __builtin_amdgcn_rcpf(s);
            if (r > best[j]) { best[j] = r; bg[j] = g; }    // strict >: first max
            if (r > fbest)   { fbest = r; fo = j * 256 + t; }
        }
        const unsigned int fb  = __float_as_uint(fbest);    // fbest >= 0
        const unsigned int flo = 0xFFFFFFFFu - (unsigned int)fo;
        const unsigned int* vp = (const unsigned int*)&vkey[g];
        const unsigned int clo = vp[0], chi = vp[1];        // 32-bit: no tear
        if (fb > chi || (fb == chi && flo > clo))
            atomicMax(&vkey[g], ((unsigned long long)fb << 32) |
                                (unsigned long long)flo);
    }

#pragma unroll
    for (int j = 0; j < AT; ++j) {
        g_mask[abase + j * 256 + t] = (best[j] > (1.0f / 3.0f)) ? 1 : 0;
        g_bidx[abase + j * 256 + t] = (unsigned char)bg[j];
    }
    __syncthreads();
    if (t < GG) {
        const unsigned long long k = vkey[t];
        const unsigned int off = 0xFFFFFFFFu - (unsigned int)(k & 0xFFFFFFFFull);
        const unsigned int ga = (unsigned int)(blockIdx.x * APB) + off;
        g_fpart[((size_t)b * GG + t) * MBLK + blockIdx.x] =
            (k & 0xFFFFFFFF00000000ull) |
            (unsigned long long)(0xFFFFFFFFu - ga);
    }
}

// ---------------------------------------------------------------------------
// Kernel 2: fold MBLK=64 partials per (b,g), set forced-positive mask bit.
// grid (G, B), block 64 (one wave; shuffle reduce).
__global__ void k_redforce() {
    const int g = blockIdx.x, b = blockIdx.y, t = threadIdx.x;
    unsigned long long k = g_fpart[((size_t)b * GG + g) * MBLK + t];
#pragma unroll
    for (int off = 32; off > 0; off >>= 1) {
        const unsigned long long o = __shfl_xor(k, off, 64);
        if (o > k) k = o;
    }
    if (t == 0) {
        const unsigned int a = 0xFFFFFFFFu - (unsigned int)(k & 0xFFFFFFFFull);
        g_mask[(size_t)b * AA + a] = 1;
    }
}

// ---------------------------------------------------------------------------
// Kernel 3: segmented per-image stats. grid (NSEG, B), block 256.
// LDS hist packed 2 bins/u32 (u16 counts; block sees <=4096 negatives, no
// overflow). Deterministic partial writeout, no global atomics, no init.
__global__ void k_stats(const float4* __restrict__ bbox,
                        const float* __restrict__ conf,
                        const float4* __restrict__ gts) {
    __shared__ float4 sg[GG];
    __shared__ unsigned int hp[NB / 2];       // 16 KB
    __shared__ float rf[256], rf2[256];
    __shared__ unsigned int ru[256];
    const int b = blockIdx.y, seg = blockIdx.x, t = threadIdx.x;
    if (t < GG) sg[t] = gts[(size_t)b * GG + t];
    for (int j = t; j < NB / 2; j += 256) hp[j] = 0u;
    __syncthreads();

    const size_t base = (size_t)b * AA + (size_t)seg * SEGA;   // anchor units
    const float4* c4 = (const float4*)(conf + base);
    const uchar4* m4 = (const uchar4*)(g_mask + base);
    const uchar4* x4 = (const uchar4*)(g_bidx + base);
    const float4* bb4 = bbox + base;

    float pos = 0.0f, loc = 0.0f;
    int np = 0;
#pragma unroll
    for (int j = 0; j < SEGA / 1024; ++j) {   // 4 iterations, 4 anchors/thread
        const int idx = j * 256 + t;
        const float4 p4 = c4[idx];
        const uchar4 mm = m4[idx];
        const uchar4 xx = x4[idx];
        const float pv[4] = {p4.x, p4.y, p4.z, p4.w};
        const unsigned char mv[4] = {mm.x, mm.y, mm.z, mm.w};
        const unsigned char xv[4] = {xx.x, xx.y, xx.z, xx.w};
#pragma unroll
        for (int c = 0; c < 4; ++c) {
            const float p = pv[c];
            if (mv[c]) {
                np += 1;
                pos += -logf(p);
                const float4 bv = bb4[4 * idx + c];
                const float4 gb = sg[xv[c]];
                const float d0 = (bv.x + bv.z) * 0.5f - (gb.x + gb.z) * 0.5f;
                const float d1 = (bv.y + bv.w) * 0.5f - (gb.y + gb.w) * 0.5f;
                const float d2 = (bv.z - bv.x) - (gb.z - gb.x);
                const float d3 = (bv.w - bv.y) - (gb.w - gb.y);
                float ds[4] = {d0, d1, d2, d3};
#pragma unroll
                for (int q = 0; q < 4; ++q) {
                    float ax = fabsf(ds[q]);
                    loc += (ax < 1.0f) ? 0.5f * ax * ax : ax - 0.5f;
                }
            } else {
                const float nb = -log1pf(-p);
                int key = (int)(__float_as_uint(nb) >> 14) - (int)KOFF;
                key = key < 0 ? 0 : (key > NB - 1 ? NB - 1 : key);
                atomicAdd(&hp[key >> 1], 1u << ((key & 1) << 4));
            }
        }
    }
    // block reduce np/pos/loc (barriers also fence the LDS hist atomics)
    ru[t] = (unsigned int)np; rf[t] = pos; rf2[t] = loc;
    __syncthreads();
    for (int w = 128; w > 0; w >>= 1) {
        if (t < w) { ru[t] += ru[t + w]; rf[t] += rf[t + w]; rf2[t] += rf2[t + w]; }
        __syncthreads();
    }
    if (t == 0) {
        g_npart[b * NSEG + seg] = (int)ru[0];
        g_spart[(b * NSEG + seg) * 2 + 0] = rf[0];
        g_spart[(b * NSEG + seg) * 2 + 1] = rf2[0];
    }
    unsigned int* outp = g_hpart + ((size_t)b * NSEG + seg) * (NB / 2);
    for (int j = t; j < NB / 2; j += 256) outp[j] = hp[j];
}

// ---------------------------------------------------------------------------
// Kernel 4: per-image fold + hard-negative top-k selection. grid B, block 1024.
__global__ void __launch_bounds__(1024) k_select() {
    __shared__ unsigned int hist[NB];         // 32 KB
    __shared__ unsigned int ru[1024];
    __shared__ unsigned int s2[32];
    __shared__ float sh_pos, sh_loc;
    __shared__ int sh_np, sh_k, sh_bsel;
    __shared__ unsigned int sh_take;
    __shared__ float rf[1024];

    const int b = blockIdx.x, t = threadIdx.x;
    // fold 16 packed partial hists -> u32 LDS hist
    for (int w = t; w < NB / 2; w += 1024) {
        unsigned int lo = 0, hi = 0;
#pragma unroll
        for (int s = 0; s < NSEG; ++s) {
            const unsigned int v = g_hpart[((size_t)b * NSEG + s) * (NB / 2) + w];
            lo += v & 0xFFFFu; hi += v >> 16;
        }
        hist[2 * w] = lo; hist[2 * w + 1] = hi;
    }
    if (t == 0) {
        int np = 0; float pos = 0.0f, loc = 0.0f;
        for (int s = 0; s < NSEG; ++s) {
            np += g_npart[b * NSEG + s];
            pos += g_spart[(b * NSEG + s) * 2 + 0];
            loc += g_spart[(b * NSEG + s) * 2 + 1];
        }
        sh_np = np; sh_pos = pos; sh_loc = loc;
    }
    __syncthreads();
    const int np_tot = sh_np;

    // descending chunk counts: thread t covers bins NB-1-8t .. NB-8-8t
    unsigned int c = 0;
    const int hi = NB - 1 - t * 8;
#pragma unroll
    for (int j = 0; j < 8; ++j) c += hist[hi - j];
    ru[t] = c;
    __syncthreads();
    if (t < 32) {
        unsigned int x = 0;
#pragma unroll
        for (int j = 0; j < 32; ++j) x += ru[t * 32 + j];
        s2[t] = x;
    }
    __syncthreads();
    if (t == 0) {
        int k = 3 * np_tot;
        const int maxneg = AA - np_tot;
        if (k > maxneg) k = maxneg;
        sh_k = k;
        int bsel = NB;            // NB => nothing selected
        unsigned int take = 0;
        if (k > 0) {
            unsigned int cum = 0;
            int u = 0;
            while (u < 31 && cum + s2[u] < (unsigned int)k) { cum += s2[u]; ++u; }
            int cc = u * 32;
            while (cc < 1023 && cum + ru[cc] < (unsigned int)k) { cum += ru[cc]; ++cc; }
            const int h2 = NB - 1 - cc * 8;
            int j = 0;
            while (j < 7 && cum + hist[h2 - j] < (unsigned int)k) { cum += hist[h2 - j]; ++j; }
            bsel = h2 - j;
            take = (unsigned int)k - cum;
        }
        sh_bsel = bsel; sh_take = take;
    }
    __syncthreads();
    const int bsel = sh_bsel;
    float negp = 0.0f;
    for (int j = t; j < NB; j += 1024)
        if (j > bsel) { unsigned int cnt = hist[j]; if (cnt) negp += (float)cnt * midval(j); }
    rf[t] = negp;
    __syncthreads();
    for (int w = 512; w > 0; w >>= 1) {
        if (t < w) rf[t] += rf[t + w];
        __syncthreads();
    }
    if (t == 0) {
        float neg = 0.0f;
        if (sh_k > 0) neg = rf[0] + (float)sh_take * midval(bsel < NB ? bsel : 0);
        g_loc[b] = sh_loc; g_pos[b] = sh_pos; g_neg[b] = neg;
        g_npos[b] = np_tot; g_nneg[b] = sh_k;
    }
}

// ---------------------------------------------------------------------------
// Kernel 5: final combine. Dual bf16 encode (R4/R5: exact match, keep).
__global__ void k_final(unsigned int* __restrict__ out) {
    if (threadIdx.x == 0) {
        float loc = 0.0f, conf = 0.0f;
        int tot = 0;
        for (int b = 0; b < BB; ++b) {
            loc += g_loc[b];
            const int np = g_npos[b], nn = g_nneg[b];
            conf += g_pos[b] / (float)(np > 1 ? np : 1) +
                    g_neg[b] / (float)(nn > 1 ? nn : 1);
            tot += np;
        }
        const float total = loc / (float)(tot > 1 ? tot : 1) + conf / (float)BB;
        unsigned int u = __float_as_uint(total);
        unsigned int r = 0x7FFFu + ((u >> 16) & 1u);
        unsigned int bf = (u + r) >> 16;            // bf16(total), RNE
        out[0] = (bf << 16) | bf;
    }
}

extern "C" void kernel_launch(void* const* d_in, const int* in_sizes, int n_in,
                              void* d_out, int out_size, void* d_ws, size_t ws_size,
                              hipStream_t stream) {
    const float4* bbox    = (const float4*)d_in[0];
    const float*  conf    = (const float*)d_in[1];
    const float4* anchors = (const float4*)d_in[2];
    const float4* gts     = (const float4*)d_in[3];

    k_matchforce<<<dim3(MBLK, BB), 256, 0, stream>>>(anchors, gts);
    k_redforce<<<dim3(GG, BB), 64, 0, stream>>>();
    k_stats<<<dim3(NSEG, BB), 256, 0, stream>>>(bbox, conf, gts);
    k_select<<<BB, 1024, 0, stream>>>();
    k_final<<<1, 64, 0, stream>>>((unsigned int*)d_out);
}

// Round 4
// 171.322 us; speedup vs baseline: 1.0569x; 1.0569x over previous
//
#include <hip/hip_runtime.h>

// B=16 images, A=65536 anchors, G=32 gts. Inputs float32; output slot read as
// bf16 low-16-bits (R4/R5: dual-encode store gives absmax 0.0 -> keep it).
#define BB 16
#define AA 65536
#define GG 32
// Histogram: key = (float_bits>>14) - KOFF, bin 0 == 2^-10, 512 bins/octave.
// Count-only, value = bin midpoint (rel err <= 2^-10 << 2% budget).
#define NB 8192
#define KOFF 59904u          // __float_as_uint(2^-10) >> 14
#define AT 4                 // anchors per thread in k_matchforce
#define APB (256 * AT)       // 1024 anchors per block
#define MBLK (AA / APB)      // 64 match blocks per image
#define NSEG 16              // stats segments per image
#define SEGA (AA / NSEG)     // 4096 anchors per stats block

// All scratch in device globals; every buffer is FULLY rewritten each call
// before being read (g_done re-armed by k_matchforce). Re-poison safe.
__device__ unsigned char      g_mask[(size_t)BB * AA];
__device__ unsigned char      g_bidx[(size_t)BB * AA];
__device__ unsigned long long g_fpart[(size_t)BB * GG * MBLK];
__device__ unsigned int       g_hpart[(size_t)BB * NSEG * (NB/2)]; // 4 MB packed
__device__ float g_spart[BB * NSEG * 2];   // pos, loc partials
__device__ int   g_npart[BB * NSEG];
__device__ float g_loc[BB], g_pos[BB], g_neg[BB];
__device__ int   g_npos[BB], g_nneg[BB];
__device__ int   g_done;                   // armed to 0 by k_matchforce

__device__ __forceinline__ float midval(int bin) {
    return __uint_as_float((((unsigned int)bin + KOFF) << 14) | 8192u);
}

// ---------------------------------------------------------------------------
// Kernel 1: fused per-anchor match + per-gt force-match partials.
// grid (MBLK, B), block 256, AT=4 anchors/thread (strided, coalesced).
// Divide-free scoring: r = inter/(areaA+areaG) is a monotone transform of IoU
// (iou = r/(1-r)), argmax-equivalent; iou>0.5 <=> r>1/3. rcp 1-ulp error is
// absorbed by the bf16 budget (R2/R3 benches: absmax 0.0).
// R3 post-mortem: FULL unroll of the 32-gt loop let the scheduler hoist all
// 32 gts' LDS loads -> 38 MB scratch writes. Fix: unroll 2 (hoist window = 2
// gts), and drop the sga[] LDS array (3 VALU recompute beats a hoisted load).
// Force match: per-gt guarded 64-bit LDS atomicMax on key =
// (r_bits<<32)|(~offset); tie-break = lowest anchor offset. Guard reads hi/lo
// as two 32-bit LDS reads (tear-free); key is monotone under atomicMax, so a
// stale guard read only causes a harmless extra atomic, never a wrong skip.
// Init key = (r=0, offset 0): the r==0 masses fail the guard -> no flood.
__global__ void __launch_bounds__(256, 4)
k_matchforce(const float4* __restrict__ anchors,
             const float4* __restrict__ gts) {
    __shared__ float4 sg[GG];
    __shared__ unsigned long long vkey[GG];
    const int b = blockIdx.y;
    const int t = threadIdx.x;
    if (blockIdx.x == 0 && b == 0 && t == 0) g_done = 0;   // arm the select ctr
    if (t < GG) {
        sg[t] = gts[(size_t)b * GG + t];
        vkey[t] = 0xFFFFFFFFull;          // r=0, block-local offset 0
    }
    __syncthreads();

    const size_t abase = (size_t)b * AA + (size_t)blockIdx.x * APB;

    float ax0[AT], ay0[AT], ax1[AT], ay1[AT], aar[AT], best[AT];
    int bg[AT];
#pragma unroll
    for (int j = 0; j < AT; ++j) {
        const float4 av = anchors[abase + j * 256 + t];
        ax0[j] = av.x; ay0[j] = av.y; ax1[j] = av.z; ay1[j] = av.w;
        aar[j] = (av.z - av.x) * (av.w - av.y);
        best[j] = -1.0f; bg[j] = 0;
    }

#pragma unroll 2
    for (int g = 0; g < GG; ++g) {
        const float4 gb = sg[g];
        const float ga = (gb.z - gb.x) * (gb.w - gb.y);
        float fbest = -1.0f;              // r >= 0 always -> j=0 wins init
        int fo = t;                       // block-local offset of j=0 anchor
#pragma unroll
        for (int j = 0; j < AT; ++j) {
            const float lx = fmaxf(ax0[j], gb.x), ly = fmaxf(ay0[j], gb.y);
            const float rx = fminf(ax1[j], gb.z), ry = fminf(ay1[j], gb.w);
            const float w = fmaxf(rx - lx, 0.0f), h = fmaxf(ry - ly, 0.0f);
            const float inter = w * h;
            const float s = aar[j] + ga;                    // areaA + areaG > 0
            const float r = inter * __builtin_amdgcn_rcpf(s);
            if (r > best[j]) { best[j] = r; bg[j] = g; }    // strict >: first max
            if (r > fbest)   { fbest = r; fo = j * 256 + t; }
        }
        const unsigned int fb  = __float_as_uint(fbest);    // fbest >= 0
        const unsigned int flo = 0xFFFFFFFFu - (unsigned int)fo;
        const unsigned int* vp = (const unsigned int*)&vkey[g];
        const unsigned int clo = vp[0], chi = vp[1];        // 32-bit: no tear
        if (fb > chi || (fb == chi && flo > clo))
            atomicMax(&vkey[g], ((unsigned long long)fb << 32) |
                                (unsigned long long)flo);
    }

#pragma unroll
    for (int j = 0; j < AT; ++j) {
        g_mask[abase + j * 256 + t] = (best[j] > (1.0f / 3.0f)) ? 1 : 0;
        g_bidx[abase + j * 256 + t] = (unsigned char)bg[j];
    }
    __syncthreads();
    if (t < GG) {
        const unsigned long long k = vkey[t];
        const unsigned int off = 0xFFFFFFFFu - (unsigned int)(k & 0xFFFFFFFFull);
        const unsigned int ga = (unsigned int)(blockIdx.x * APB) + off;
        g_fpart[((size_t)b * GG + t) * MBLK + blockIdx.x] =
            (k & 0xFFFFFFFF00000000ull) |
            (unsigned long long)(0xFFFFFFFFu - ga);
    }
}

// ---------------------------------------------------------------------------
// Kernel 2: segmented per-image stats. grid (NSEG, B), block 256.
// Folds the force-match partials itself (replaces the old k_redforce kernel):
// thread t folds chunk (t&7) of gt (t>>3) over 8 partials, 3-level shfl_xor
// within 8-lane groups, then chunk-0 lanes mark winners that fall inside this
// block's segment in a 512 B LDS bitmap. Positive = g_mask OR bitmap bit.
// LDS hist packed 2 bins/u32 (u16 counts; block sees <=4096 negatives, no
// overflow). Deterministic partial writeout, no global atomics, no init.
__global__ void k_stats(const float4* __restrict__ bbox,
                        const float* __restrict__ conf,
                        const float4* __restrict__ gts) {
    __shared__ float4 sg[GG];
    __shared__ unsigned int hp[NB / 2];       // 16 KB
    __shared__ unsigned int bmap[SEGA / 32];  // 512 B forced-positive bitmap
    __shared__ float rf[256], rf2[256];
    __shared__ unsigned int ru[256];
    const int b = blockIdx.y, seg = blockIdx.x, t = threadIdx.x;
    if (t < GG) sg[t] = gts[(size_t)b * GG + t];
    for (int j = t; j < NB / 2; j += 256) hp[j] = 0u;
    if (t < SEGA / 32) bmap[t] = 0u;
    __syncthreads();

    // fold force-match winners; mark ones landing in this segment
    {
        const int gg = t >> 3, p = t & 7;     // 256 threads = 32 gts x 8 chunks
        const unsigned long long* fp =
            &g_fpart[((size_t)b * GG + gg) * MBLK + p * 8];
        unsigned long long k = 0;
#pragma unroll
        for (int m = 0; m < 8; ++m) { const unsigned long long v = fp[m]; if (v > k) k = v; }
#pragma unroll
        for (int off = 1; off < 8; off <<= 1) {
            const unsigned long long o = __shfl_xor(k, off, 64);
            if (o > k) k = o;
        }
        if (p == 0) {
            const unsigned int a = 0xFFFFFFFFu - (unsigned int)(k & 0xFFFFFFFFull);
            const int la = (int)a - seg * SEGA;
            if (la >= 0 && la < SEGA) atomicOr(&bmap[la >> 5], 1u << (la & 31));
        }
    }
    __syncthreads();

    const size_t base = (size_t)b * AA + (size_t)seg * SEGA;   // anchor units
    const float4* c4 = (const float4*)(conf + base);
    const uchar4* m4 = (const uchar4*)(g_mask + base);
    const uchar4* x4 = (const uchar4*)(g_bidx + base);
    const float4* bb4 = bbox + base;

    float pos = 0.0f, loc = 0.0f;
    int np = 0;
#pragma unroll
    for (int j = 0; j < SEGA / 1024; ++j) {   // 4 iterations, 4 anchors/thread
        const int idx = j * 256 + t;
        const float4 p4 = c4[idx];
        const uchar4 mm = m4[idx];
        const uchar4 xx = x4[idx];
        const unsigned int bw = (bmap[idx >> 3] >> ((idx & 7) * 4)) & 0xFu;
        const float pv[4] = {p4.x, p4.y, p4.z, p4.w};
        const unsigned char mv[4] = {mm.x, mm.y, mm.z, mm.w};
        const unsigned char xv[4] = {xx.x, xx.y, xx.z, xx.w};
#pragma unroll
        for (int c = 0; c < 4; ++c) {
            const float p = pv[c];
            if (mv[c] | ((bw >> c) & 1u)) {
                np += 1;
                pos += -logf(p);
                const float4 bv = bb4[4 * idx + c];
                const float4 gb = sg[xv[c]];
                const float d0 = (bv.x + bv.z) * 0.5f - (gb.x + gb.z) * 0.5f;
                const float d1 = (bv.y + bv.w) * 0.5f - (gb.y + gb.w) * 0.5f;
                const float d2 = (bv.z - bv.x) - (gb.z - gb.x);
                const float d3 = (bv.w - bv.y) - (gb.w - gb.y);
                float ds[4] = {d0, d1, d2, d3};
#pragma unroll
                for (int q = 0; q < 4; ++q) {
                    float ax = fabsf(ds[q]);
                    loc += (ax < 1.0f) ? 0.5f * ax * ax : ax - 0.5f;
                }
            } else {
                const float nb = -log1pf(-p);
                int key = (int)(__float_as_uint(nb) >> 14) - (int)KOFF;
                key = key < 0 ? 0 : (key > NB - 1 ? NB - 1 : key);
                atomicAdd(&hp[key >> 1], 1u << ((key & 1) << 4));
            }
        }
    }
    // block reduce np/pos/loc (barriers also fence the LDS hist atomics)
    ru[t] = (unsigned int)np; rf[t] = pos; rf2[t] = loc;
    __syncthreads();
    for (int w = 128; w > 0; w >>= 1) {
        if (t < w) { ru[t] += ru[t + w]; rf[t] += rf[t + w]; rf2[t] += rf2[t + w]; }
        __syncthreads();
    }
    if (t == 0) {
        g_npart[b * NSEG + seg] = (int)ru[0];
        g_spart[(b * NSEG + seg) * 2 + 0] = rf[0];
        g_spart[(b * NSEG + seg) * 2 + 1] = rf2[0];
    }
    unsigned int* outp = g_hpart + ((size_t)b * NSEG + seg) * (NB / 2);
    for (int j = t; j < NB / 2; j += 256) outp[j] = hp[j];
}

// ---------------------------------------------------------------------------
// Kernel 3: per-image fold + hard-negative top-k + (last block) final combine.
// grid B, block 1024. Cross-block handoff: writer stores per-image results,
// __threadfence(), atomicAdd(g_done); the 16th block re-fences and reads all
// images' results with agent-scope atomic loads (XCD-coherence safe), then
// writes the dual-bf16-encoded output (R4/R5: exact match, keep).
__global__ void __launch_bounds__(1024) k_select(unsigned int* __restrict__ out) {
    __shared__ unsigned int hist[NB];         // 32 KB
    __shared__ unsigned int ru[1024];
    __shared__ unsigned int s2[32];
    __shared__ float sh_pos, sh_loc;
    __shared__ int sh_np, sh_k, sh_bsel;
    __shared__ unsigned int sh_take;
    __shared__ float rf[1024];

    const int b = blockIdx.x, t = threadIdx.x;
    // fold 16 packed partial hists -> u32 LDS hist
    for (int w = t; w < NB / 2; w += 1024) {
        unsigned int lo = 0, hi = 0;
#pragma unroll
        for (int s = 0; s < NSEG; ++s) {
            const unsigned int v = g_hpart[((size_t)b * NSEG + s) * (NB / 2) + w];
            lo += v & 0xFFFFu; hi += v >> 16;
        }
        hist[2 * w] = lo; hist[2 * w + 1] = hi;
    }
    if (t == 0) {
        int np = 0; float pos = 0.0f, loc = 0.0f;
        for (int s = 0; s < NSEG; ++s) {
            np += g_npart[b * NSEG + s];
            pos += g_spart[(b * NSEG + s) * 2 + 0];
            loc += g_spart[(b * NSEG + s) * 2 + 1];
        }
        sh_np = np; sh_pos = pos; sh_loc = loc;
    }
    __syncthreads();
    const int np_tot = sh_np;

    // descending chunk counts: thread t covers bins NB-1-8t .. NB-8-8t
    unsigned int c = 0;
    const int hi = NB - 1 - t * 8;
#pragma unroll
    for (int j = 0; j < 8; ++j) c += hist[hi - j];
    ru[t] = c;
    __syncthreads();
    if (t < 32) {
        unsigned int x = 0;
#pragma unroll
        for (int j = 0; j < 32; ++j) x += ru[t * 32 + j];
        s2[t] = x;
    }
    __syncthreads();
    if (t == 0) {
        int k = 3 * np_tot;
        const int maxneg = AA - np_tot;
        if (k > maxneg) k = maxneg;
        sh_k = k;
        int bsel = NB;            // NB => nothing selected
        unsigned int take = 0;
        if (k > 0) {
            unsigned int cum = 0;
            int u = 0;
            while (u < 31 && cum + s2[u] < (unsigned int)k) { cum += s2[u]; ++u; }
            int cc = u * 32;
            while (cc < 1023 && cum + ru[cc] < (unsigned int)k) { cum += ru[cc]; ++cc; }
            const int h2 = NB - 1 - cc * 8;
            int j = 0;
            while (j < 7 && cum + hist[h2 - j] < (unsigned int)k) { cum += hist[h2 - j]; ++j; }
            bsel = h2 - j;
            take = (unsigned int)k - cum;
        }
        sh_bsel = bsel; sh_take = take;
    }
    __syncthreads();
    const int bsel = sh_bsel;
    float negp = 0.0f;
    for (int j = t; j < NB; j += 1024)
        if (j > bsel) { unsigned int cnt = hist[j]; if (cnt) negp += (float)cnt * midval(j); }
    rf[t] = negp;
    __syncthreads();
    for (int w = 512; w > 0; w >>= 1) {
        if (t < w) rf[t] += rf[t + w];
        __syncthreads();
    }
    if (t == 0) {
        float neg = 0.0f;
        if (sh_k > 0) neg = rf[0] + (float)sh_take * midval(bsel < NB ? bsel : 0);
        g_loc[b] = sh_loc; g_pos[b] = sh_pos; g_neg[b] = neg;
        g_npos[b] = np_tot; g_nneg[b] = sh_k;

        __threadfence();                        // publish before counting in
        const int old = atomicAdd(&g_done, 1);
        if (old == BB - 1) {                    // last image: final combine
            __threadfence();
            float loc = 0.0f, conf = 0.0f;
            int tot = 0;
            for (int bb = 0; bb < BB; ++bb) {
                const float lv = __hip_atomic_load(&g_loc[bb],  __ATOMIC_RELAXED, __HIP_MEMORY_SCOPE_AGENT);
                const float pv = __hip_atomic_load(&g_pos[bb],  __ATOMIC_RELAXED, __HIP_MEMORY_SCOPE_AGENT);
                const float nv = __hip_atomic_load(&g_neg[bb],  __ATOMIC_RELAXED, __HIP_MEMORY_SCOPE_AGENT);
                const int   np = __hip_atomic_load(&g_npos[bb], __ATOMIC_RELAXED, __HIP_MEMORY_SCOPE_AGENT);
                const int   nn = __hip_atomic_load(&g_nneg[bb], __ATOMIC_RELAXED, __HIP_MEMORY_SCOPE_AGENT);
                loc += lv;
                conf += pv / (float)(np > 1 ? np : 1) +
                        nv / (float)(nn > 1 ? nn : 1);
                tot += np;
            }
            const float total = loc / (float)(tot > 1 ? tot : 1) + conf / (float)BB;
            const unsigned int u = __float_as_uint(total);
            const unsigned int r = 0x7FFFu + ((u >> 16) & 1u);
            const unsigned int bf = (u + r) >> 16;      // bf16(total), RNE
            out[0] = (bf << 16) | bf;
        }
    }
}

extern "C" void kernel_launch(void* const* d_in, const int* in_sizes, int n_in,
                              void* d_out, int out_size, void* d_ws, size_t ws_size,
                              hipStream_t stream) {
    const float4* bbox    = (const float4*)d_in[0];
    const float*  conf    = (const float*)d_in[1];
    const float4* anchors = (const float4*)d_in[2];
    const float4* gts     = (const float4*)d_in[3];

    k_matchforce<<<dim3(MBLK, BB), 256, 0, stream>>>(anchors, gts);
    k_stats<<<dim3(NSEG, BB), 256, 0, stream>>>(bbox, conf, gts);
    k_select<<<BB, 1024, 0, stream>>>((unsigned int*)d_out);
}

// Round 5
// 170.783 us; speedup vs baseline: 1.0602x; 1.0032x over previous
//
#include <hip/hip_runtime.h>

// B=16 images, A=65536 anchors, G=32 gts. Inputs float32; output slot read as
// bf16 low-16-bits (R4/R5: dual-encode store gives absmax 0.0 -> keep it).
#define BB 16
#define AA 65536
#define GG 32
// Histogram: key = (float_bits>>14) - KOFF, bin 0 == 2^-10, 512 bins/octave.
// Count-only, value = bin midpoint (rel err <= 2^-10 << 2% budget).
#define NB 8192
#define KOFF 59904u          // __float_as_uint(2^-10) >> 14
#define AT 4                 // anchors per thread in k_matchforce
#define APB (256 * AT)       // 1024 anchors per block
#define MBLK (AA / APB)      // 64 match blocks per image
#define NSEG 16              // stats segments per image
#define SEGA (AA / NSEG)     // 4096 anchors per stats block

// All scratch in device globals; every buffer is FULLY rewritten each call
// before being read (g_done re-armed by k_matchforce). Re-poison safe.
__device__ unsigned char      g_mask[(size_t)BB * AA];
__device__ unsigned char      g_bidx[(size_t)BB * AA];
__device__ unsigned long long g_fpart[(size_t)BB * GG * MBLK];
__device__ unsigned int       g_hpart[(size_t)BB * NSEG * (NB/2)]; // 4 MB packed
__device__ float g_spart[BB * NSEG * 2];   // pos, loc partials
__device__ int   g_npart[BB * NSEG];
__device__ float g_loc[BB], g_pos[BB], g_neg[BB];
__device__ int   g_npos[BB], g_nneg[BB];
__device__ int   g_done;                   // armed to 0 by k_matchforce

__device__ __forceinline__ float midval(int bin) {
    return __uint_as_float((((unsigned int)bin + KOFF) << 14) | 8192u);
}

// ---------------------------------------------------------------------------
// Kernel 1: fused per-anchor match + per-gt force-match partials.
// grid (MBLK, B), block 256, AT=4 anchors/thread (strided, coalesced).
// Divide-free scoring: r = inter/(areaA+areaG) is a monotone transform of IoU
// (iou = r/(1-r)), argmax-equivalent; iou>0.5 <=> r>1/3. rcp 1-ulp error is
// absorbed by the bf16 budget (R2-R4 benches: absmax 0.0).
// R4 post-mortem: the guarded-atomic path was LATENCY-bound (per-SIMD issue
// ~15%): every gt iteration chained {vkey guard ds_read (~120cy) -> cmp ->
// returning 64b atomic}, only 2-deep in flight. Fix: NO guard read, NO
// returning atomic -- reduce the thread's 4 candidates in registers, then
// fire-and-forget ds_max_u64 on key=(r_bits<<32)|(~offset), issued only when
// fbest>0 (~34% of threads; r==0 masses skip -> bounded same-address
// serialization, hidden under VALU issue). No LDS reads, no waits inside the
// loop; lgkmcnt drains once at the final barrier. Tie-break = lowest anchor
// offset, exact (full 64-bit key, atomicMax semantics unchanged).
__global__ void __launch_bounds__(256, 4)
k_matchforce(const float4* __restrict__ anchors,
             const float4* __restrict__ gts) {
    __shared__ float4 sg[GG];
    __shared__ unsigned long long vkey[GG];
    const int b = blockIdx.y;
    const int t = threadIdx.x;
    if (blockIdx.x == 0 && b == 0 && t == 0) g_done = 0;   // arm the select ctr
    if (t < GG) {
        sg[t] = gts[(size_t)b * GG + t];
        vkey[t] = 0xFFFFFFFFull;          // r=0, block-local offset 0
    }
    __syncthreads();

    const size_t abase = (size_t)b * AA + (size_t)blockIdx.x * APB;

    float ax0[AT], ay0[AT], ax1[AT], ay1[AT], aar[AT], best[AT];
    int bg[AT];
#pragma unroll
    for (int j = 0; j < AT; ++j) {
        const float4 av = anchors[abase + j * 256 + t];
        ax0[j] = av.x; ay0[j] = av.y; ax1[j] = av.z; ay1[j] = av.w;
        aar[j] = (av.z - av.x) * (av.w - av.y);
        best[j] = -1.0f; bg[j] = 0;
    }

#pragma unroll 2
    for (int g = 0; g < GG; ++g) {
        const float4 gb = sg[g];
        const float ga = (gb.z - gb.x) * (gb.w - gb.y);
        float fbest = -1.0f;              // r >= 0 always -> j=0 wins init
        int fo = t;                       // block-local offset of j=0 anchor
#pragma unroll
        for (int j = 0; j < AT; ++j) {
            const float lx = fmaxf(ax0[j], gb.x), ly = fmaxf(ay0[j], gb.y);
            const float rx = fminf(ax1[j], gb.z), ry = fminf(ay1[j], gb.w);
            const float w = fmaxf(rx - lx, 0.0f), h = fmaxf(ry - ly, 0.0f);
            const float inter = w * h;
            const float s = aar[j] + ga;                    // areaA + areaG > 0
            const float r = inter * __builtin_amdgcn_rcpf(s);
            if (r > best[j]) { best[j] = r; bg[j] = g; }    // strict >: first max
            if (r > fbest)   { fbest = r; fo = j * 256 + t; }
        }
        if (fbest > 0.0f) {               // fire-and-forget; no return, no read
            const unsigned long long key =
                ((unsigned long long)__float_as_uint(fbest) << 32) |
                (unsigned long long)(0xFFFFFFFFu - (unsigned int)fo);
            atomicMax(&vkey[g], key);
        }
    }

#pragma unroll
    for (int j = 0; j < AT; ++j) {
        g_mask[abase + j * 256 + t] = (best[j] > (1.0f / 3.0f)) ? 1 : 0;
        g_bidx[abase + j * 256 + t] = (unsigned char)bg[j];
    }
    __syncthreads();                      // drains lgkmcnt: all ds_max done
    if (t < GG) {
        const unsigned long long k = vkey[t];
        const unsigned int off = 0xFFFFFFFFu - (unsigned int)(k & 0xFFFFFFFFull);
        const unsigned int ga = (unsigned int)(blockIdx.x * APB) + off;
        g_fpart[((size_t)b * GG + t) * MBLK + blockIdx.x] =
            (k & 0xFFFFFFFF00000000ull) |
            (unsigned long long)(0xFFFFFFFFu - ga);
    }
}

// ---------------------------------------------------------------------------
// Kernel 2: segmented per-image stats. grid (NSEG, B), block 256.
// Folds the force-match partials itself (replaces the old k_redforce kernel):
// thread t folds chunk (t&7) of gt (t>>3) over 8 partials, 3-level shfl_xor
// within 8-lane groups, then chunk-0 lanes mark winners that fall inside this
// block's segment in a 512 B LDS bitmap. Positive = g_mask OR bitmap bit.
// LDS hist packed 2 bins/u32 (u16 counts; block sees <=4096 negatives, no
// overflow). Deterministic partial writeout, no global atomics, no init.
__global__ void k_stats(const float4* __restrict__ bbox,
                        const float* __restrict__ conf,
                        const float4* __restrict__ gts) {
    __shared__ float4 sg[GG];
    __shared__ unsigned int hp[NB / 2];       // 16 KB
    __shared__ unsigned int bmap[SEGA / 32];  // 512 B forced-positive bitmap
    __shared__ float rf[256], rf2[256];
    __shared__ unsigned int ru[256];
    const int b = blockIdx.y, seg = blockIdx.x, t = threadIdx.x;
    if (t < GG) sg[t] = gts[(size_t)b * GG + t];
    for (int j = t; j < NB / 2; j += 256) hp[j] = 0u;
    if (t < SEGA / 32) bmap[t] = 0u;
    __syncthreads();

    // fold force-match winners; mark ones landing in this segment
    {
        const int gg = t >> 3, p = t & 7;     // 256 threads = 32 gts x 8 chunks
        const unsigned long long* fp =
            &g_fpart[((size_t)b * GG + gg) * MBLK + p * 8];
        unsigned long long k = 0;
#pragma unroll
        for (int m = 0; m < 8; ++m) { const unsigned long long v = fp[m]; if (v > k) k = v; }
#pragma unroll
        for (int off = 1; off < 8; off <<= 1) {
            const unsigned long long o = __shfl_xor(k, off, 64);
            if (o > k) k = o;
        }
        if (p == 0) {
            const unsigned int a = 0xFFFFFFFFu - (unsigned int)(k & 0xFFFFFFFFull);
            const int la = (int)a - seg * SEGA;
            if (la >= 0 && la < SEGA) atomicOr(&bmap[la >> 5], 1u << (la & 31));
        }
    }
    __syncthreads();

    const size_t base = (size_t)b * AA + (size_t)seg * SEGA;   // anchor units
    const float4* c4 = (const float4*)(conf + base);
    const uchar4* m4 = (const uchar4*)(g_mask + base);
    const uchar4* x4 = (const uchar4*)(g_bidx + base);
    const float4* bb4 = bbox + base;

    float pos = 0.0f, loc = 0.0f;
    int np = 0;
#pragma unroll
    for (int j = 0; j < SEGA / 1024; ++j) {   // 4 iterations, 4 anchors/thread
        const int idx = j * 256 + t;
        const float4 p4 = c4[idx];
        const uchar4 mm = m4[idx];
        const uchar4 xx = x4[idx];
        const unsigned int bw = (bmap[idx >> 3] >> ((idx & 7) * 4)) & 0xFu;
        const float pv[4] = {p4.x, p4.y, p4.z, p4.w};
        const unsigned char mv[4] = {mm.x, mm.y, mm.z, mm.w};
        const unsigned char xv[4] = {xx.x, xx.y, xx.z, xx.w};
#pragma unroll
        for (int c = 0; c < 4; ++c) {
            const float p = pv[c];
            if (mv[c] | ((bw >> c) & 1u)) {
                np += 1;
                pos += -logf(p);
                const float4 bv = bb4[4 * idx + c];
                const float4 gb = sg[xv[c]];
                const float d0 = (bv.x + bv.z) * 0.5f - (gb.x + gb.z) * 0.5f;
                const float d1 = (bv.y + bv.w) * 0.5f - (gb.y + gb.w) * 0.5f;
                const float d2 = (bv.z - bv.x) - (gb.z - gb.x);
                const float d3 = (bv.w - bv.y) - (gb.w - gb.y);
                float ds[4] = {d0, d1, d2, d3};
#pragma unroll
                for (int q = 0; q < 4; ++q) {
                    float ax = fabsf(ds[q]);
                    loc += (ax < 1.0f) ? 0.5f * ax * ax : ax - 0.5f;
                }
            } else {
                const float nb = -log1pf(-p);
                int key = (int)(__float_as_uint(nb) >> 14) - (int)KOFF;
                key = key < 0 ? 0 : (key > NB - 1 ? NB - 1 : key);
                atomicAdd(&hp[key >> 1], 1u << ((key & 1) << 4));
            }
        }
    }
    // block reduce np/pos/loc (barriers also fence the LDS hist atomics)
    ru[t] = (unsigned int)np; rf[t] = pos; rf2[t] = loc;
    __syncthreads();
    for (int w = 128; w > 0; w >>= 1) {
        if (t < w) { ru[t] += ru[t + w]; rf[t] += rf[t + w]; rf2[t] += rf2[t + w]; }
        __syncthreads();
    }
    if (t == 0) {
        g_npart[b * NSEG + seg] = (int)ru[0];
        g_spart[(b * NSEG + seg) * 2 + 0] = rf[0];
        g_spart[(b * NSEG + seg) * 2 + 1] = rf2[0];
    }
    unsigned int* outp = g_hpart + ((size_t)b * NSEG + seg) * (NB / 2);
    for (int j = t; j < NB / 2; j += 256) outp[j] = hp[j];
}

// ---------------------------------------------------------------------------
// Kernel 3: per-image fold + hard-negative top-k + (last block) final combine.
// grid B, block 1024. Cross-block handoff: writer stores per-image results,
// __threadfence(), atomicAdd(g_done); the 16th block re-fences and reads all
// images' results with agent-scope atomic loads (XCD-coherence safe), then
// writes the dual-bf16-encoded output (R4/R5: exact match, keep).
__global__ void __launch_bounds__(1024) k_select(unsigned int* __restrict__ out) {
    __shared__ unsigned int hist[NB];         // 32 KB
    __shared__ unsigned int ru[1024];
    __shared__ unsigned int s2[32];
    __shared__ float sh_pos, sh_loc;
    __shared__ int sh_np, sh_k, sh_bsel;
    __shared__ unsigned int sh_take;
    __shared__ float rf[1024];

    const int b = blockIdx.x, t = threadIdx.x;
    // fold 16 packed partial hists -> u32 LDS hist
    for (int w = t; w < NB / 2; w += 1024) {
        unsigned int lo = 0, hi = 0;
#pragma unroll
        for (int s = 0; s < NSEG; ++s) {
            const unsigned int v = g_hpart[((size_t)b * NSEG + s) * (NB / 2) + w];
            lo += v & 0xFFFFu; hi += v >> 16;
        }
        hist[2 * w] = lo; hist[2 * w + 1] = hi;
    }
    if (t == 0) {
        int np = 0; float pos = 0.0f, loc = 0.0f;
        for (int s = 0; s < NSEG; ++s) {
            np += g_npart[b * NSEG + s];
            pos += g_spart[(b * NSEG + s) * 2 + 0];
            loc += g_spart[(b * NSEG + s) * 2 + 1];
        }
        sh_np = np; sh_pos = pos; sh_loc = loc;
    }
    __syncthreads();
    const int np_tot = sh_np;

    // descending chunk counts: thread t covers bins NB-1-8t .. NB-8-8t
    unsigned int c = 0;
    const int hi = NB - 1 - t * 8;
#pragma unroll
    for (int j = 0; j < 8; ++j) c += hist[hi - j];
    ru[t] = c;
    __syncthreads();
    if (t < 32) {
        unsigned int x = 0;
#pragma unroll
        for (int j = 0; j < 32; ++j) x += ru[t * 32 + j];
        s2[t] = x;
    }
    __syncthreads();
    if (t == 0) {
        int k = 3 * np_tot;
        const int maxneg = AA - np_tot;
        if (k > maxneg) k = maxneg;
        sh_k = k;
        int bsel = NB;            // NB => nothing selected
        unsigned int take = 0;
        if (k > 0) {
            unsigned int cum = 0;
            int u = 0;
            while (u < 31 && cum + s2[u] < (unsigned int)k) { cum += s2[u]; ++u; }
            int cc = u * 32;
            while (cc < 1023 && cum + ru[cc] < (unsigned int)k) { cum += ru[cc]; ++cc; }
            const int h2 = NB - 1 - cc * 8;
            int j = 0;
            while (j < 7 && cum + hist[h2 - j] < (unsigned int)k) { cum += hist[h2 - j]; ++j; }
            bsel = h2 - j;
            take = (unsigned int)k - cum;
        }
        sh_bsel = bsel; sh_take = take;
    }
    __syncthreads();
    const int bsel = sh_bsel;
    float negp = 0.0f;
    for (int j = t; j < NB; j += 1024)
        if (j > bsel) { unsigned int cnt = hist[j]; if (cnt) negp += (float)cnt * midval(j); }
    rf[t] = negp;
    __syncthreads();
    for (int w = 512; w > 0; w >>= 1) {
        if (t < w) rf[t] += rf[t + w];
        __syncthreads();
    }
    if (t == 0) {
        float neg = 0.0f;
        if (sh_k > 0) neg = rf[0] + (float)sh_take * midval(bsel < NB ? bsel : 0);
        g_loc[b] = sh_loc; g_pos[b] = sh_pos; g_neg[b] = neg;
        g_npos[b] = np_tot; g_nneg[b] = sh_k;

        __threadfence();                        // publish before counting in
        const int old = atomicAdd(&g_done, 1);
        if (old == BB - 1) {                    // last image: final combine
            __threadfence();
            float loc = 0.0f, conf = 0.0f;
            int tot = 0;
            for (int bb = 0; bb < BB; ++bb) {
                const float lv = __hip_atomic_load(&g_loc[bb],  __ATOMIC_RELAXED, __HIP_MEMORY_SCOPE_AGENT);
                const float pv = __hip_atomic_load(&g_pos[bb],  __ATOMIC_RELAXED, __HIP_MEMORY_SCOPE_AGENT);
                const float nv = __hip_atomic_load(&g_neg[bb],  __ATOMIC_RELAXED, __HIP_MEMORY_SCOPE_AGENT);
                const int   np = __hip_atomic_load(&g_npos[bb], __ATOMIC_RELAXED, __HIP_MEMORY_SCOPE_AGENT);
                const int   nn = __hip_atomic_load(&g_nneg[bb], __ATOMIC_RELAXED, __HIP_MEMORY_SCOPE_AGENT);
                loc += lv;
                conf += pv / (float)(np > 1 ? np : 1) +
                        nv / (float)(nn > 1 ? nn : 1);
                tot += np;
            }
            const float total = loc / (float)(tot > 1 ? tot : 1) + conf / (float)BB;
            const unsigned int u = __float_as_uint(total);
            const unsigned int r = 0x7FFFu + ((u >> 16) & 1u);
            const unsigned int bf = (u + r) >> 16;      // bf16(total), RNE
            out[0] = (bf << 16) | bf;
        }
    }
}

extern "C" void kernel_launch(void* const* d_in, const int* in_sizes, int n_in,
                              void* d_out, int out_size, void* d_ws, size_t ws_size,
                              hipStream_t stream) {
    const float4* bbox    = (const float4*)d_in[0];
    const float*  conf    = (const float*)d_in[1];
    const float4* anchors = (const float4*)d_in[2];
    const float4* gts     = (const float4*)d_in[3];

    k_matchforce<<<dim3(MBLK, BB), 256, 0, stream>>>(anchors, gts);
    k_stats<<<dim3(NSEG, BB), 256, 0, stream>>>(bbox, conf, gts);
    k_select<<<BB, 1024, 0, stream>>>((unsigned int*)d_out);
}

// Round 6
// 132.149 us; speedup vs baseline: 1.3702x; 1.2924x over previous
//
#include <hip/hip_runtime.h>

// B=16 images, A=65536 anchors, G=32 gts. Inputs float32; output slot read as
// bf16 low-16-bits (R4/R5: dual-encode store gives absmax 0.0 -> keep it).
#define BB 16
#define AA 65536
#define GG 32
// Histogram: key = (float_bits>>14) - KOFF, bin 0 == 2^-10, 512 bins/octave.
// Count-only, value = bin midpoint (rel err <= 2^-10 << 2% budget).
#define NB 8192
#define KOFF 59904u          // __float_as_uint(2^-10) >> 14
#define AT 4                 // anchors per thread in k_matchforce
#define APB (256 * AT)       // 1024 anchors per block
#define MBLK (AA / APB)      // 64 match blocks per image
#define NSEG 16              // stats segments per image
#define SEGA (AA / NSEG)     // 4096 anchors per stats block

// All scratch in device globals; every buffer is FULLY rewritten each call
// before being read (g_done re-armed by k_matchforce). Re-poison safe.
__device__ unsigned char      g_mask[(size_t)BB * AA];
__device__ unsigned char      g_bidx[(size_t)BB * AA];
__device__ unsigned long long g_fpart[(size_t)BB * GG * MBLK];
__device__ unsigned int       g_hpart[(size_t)BB * NSEG * (NB/2)]; // 4 MB packed
__device__ float g_spart[BB * NSEG * 2];   // pos, loc partials
__device__ int   g_npart[BB * NSEG];
__device__ float g_loc[BB], g_pos[BB], g_neg[BB];
__device__ int   g_npos[BB], g_nneg[BB];
__device__ int   g_done;                   // armed to 0 by k_matchforce

__device__ __forceinline__ float midval(int bin) {
    return __uint_as_float((((unsigned int)bin + KOFF) << 14) | 8192u);
}

// ---------------------------------------------------------------------------
// Kernel 1: fused per-anchor match + per-gt force-match partials.
// grid (MBLK, B), block 256, AT=4 anchors/thread (strided, coalesced).
// Divide-free scoring: r = inter/(areaA+areaG) is a monotone transform of IoU
// (iou = r/(1-r)), argmax-equivalent; iou>0.5 <=> r>1/3. rcp 1-ulp error is
// absorbed by the bf16 budget (R2-R5 benches: absmax 0.0).
// R5 post-mortem: BOTH LDS-atomic schemes (guarded-returning and
// fire-and-forget) stuck at 73us -- same-address lane-atomic serialization at
// the CU's DS unit (~11K 64-bit lane-ops/CU) is the shared cost. Fix: ZERO
// atomics. Per gt: reduce the thread's 4 candidates in registers to one
// packed key (r_bits<<32)|(~offset)  (tie-break = lowest offset, exact), then
// a 6-level __shfl_xor u64 butterfly (conflict-free ds_swizzle, pipelined,
// 2 gts in flight via unroll 2); lane 0 writes wkey[wave][g]; after the
// barrier t<32 folds the 4 wave partials. R0-proven structure, amortized 4x.
__global__ void __launch_bounds__(256, 4)
k_matchforce(const float4* __restrict__ anchors,
             const float4* __restrict__ gts) {
    __shared__ float4 sg[GG];
    __shared__ unsigned long long wkey[4][GG];
    const int b = blockIdx.y;
    const int t = threadIdx.x;
    const int wave = t >> 6, lane = t & 63;
    if (blockIdx.x == 0 && b == 0 && t == 0) g_done = 0;   // arm the select ctr
    if (t < GG) sg[t] = gts[(size_t)b * GG + t];
    __syncthreads();

    const size_t abase = (size_t)b * AA + (size_t)blockIdx.x * APB;

    float ax0[AT], ay0[AT], ax1[AT], ay1[AT], aar[AT], best[AT];
    int bg[AT];
#pragma unroll
    for (int j = 0; j < AT; ++j) {
        const float4 av = anchors[abase + j * 256 + t];
        ax0[j] = av.x; ay0[j] = av.y; ax1[j] = av.z; ay1[j] = av.w;
        aar[j] = (av.z - av.x) * (av.w - av.y);
        best[j] = -1.0f; bg[j] = 0;
    }

#pragma unroll 2
    for (int g = 0; g < GG; ++g) {
        const float4 gb = sg[g];
        const float ga = (gb.z - gb.x) * (gb.w - gb.y);
        float fbest = -1.0f;              // r >= 0 always -> j=0 wins init
        int fo = t;                       // block-local offset of j=0 anchor
#pragma unroll
        for (int j = 0; j < AT; ++j) {
            const float lx = fmaxf(ax0[j], gb.x), ly = fmaxf(ay0[j], gb.y);
            const float rx = fminf(ax1[j], gb.z), ry = fminf(ay1[j], gb.w);
            const float w = fmaxf(rx - lx, 0.0f), h = fmaxf(ry - ly, 0.0f);
            const float inter = w * h;
            const float s = aar[j] + ga;                    // areaA + areaG > 0
            const float r = inter * __builtin_amdgcn_rcpf(s);
            if (r > best[j]) { best[j] = r; bg[j] = g; }    // strict >: first max
            if (r > fbest)   { fbest = r; fo = j * 256 + t; }
        }
        // packed key: fbest >= 0 so float bits are unsigned-monotone; low word
        // = ~offset so larger key == smaller anchor offset on value ties.
        unsigned long long key =
            ((unsigned long long)__float_as_uint(fbest) << 32) |
            (unsigned long long)(0xFFFFFFFFu - (unsigned int)fo);
#pragma unroll
        for (int off = 1; off < 64; off <<= 1) {
            const unsigned long long o = __shfl_xor(key, off, 64);
            if (o > key) key = o;
        }
        if (lane == 0) wkey[wave][g] = key;
    }

#pragma unroll
    for (int j = 0; j < AT; ++j) {
        g_mask[abase + j * 256 + t] = (best[j] > (1.0f / 3.0f)) ? 1 : 0;
        g_bidx[abase + j * 256 + t] = (unsigned char)bg[j];
    }
    __syncthreads();
    if (t < GG) {
        unsigned long long k = wkey[0][t];
#pragma unroll
        for (int w = 1; w < 4; ++w) {
            const unsigned long long k1 = wkey[w][t];
            if (k1 > k) k = k1;
        }
        const unsigned int off = 0xFFFFFFFFu - (unsigned int)(k & 0xFFFFFFFFull);
        const unsigned int ga = (unsigned int)(blockIdx.x * APB) + off;
        g_fpart[((size_t)b * GG + t) * MBLK + blockIdx.x] =
            (k & 0xFFFFFFFF00000000ull) |
            (unsigned long long)(0xFFFFFFFFu - ga);
    }
}

// ---------------------------------------------------------------------------
// Kernel 2: segmented per-image stats. grid (NSEG, B), block 256.
// Folds the force-match partials itself (replaces the old k_redforce kernel):
// thread t folds chunk (t&7) of gt (t>>3) over 8 partials, 3-level shfl_xor
// within 8-lane groups, then chunk-0 lanes mark winners that fall inside this
// block's segment in a 512 B LDS bitmap. Positive = g_mask OR bitmap bit.
// LDS hist packed 2 bins/u32 (u16 counts; block sees <=4096 negatives, no
// overflow). Deterministic partial writeout, no global atomics, no init.
__global__ void k_stats(const float4* __restrict__ bbox,
                        const float* __restrict__ conf,
                        const float4* __restrict__ gts) {
    __shared__ float4 sg[GG];
    __shared__ unsigned int hp[NB / 2];       // 16 KB
    __shared__ unsigned int bmap[SEGA / 32];  // 512 B forced-positive bitmap
    __shared__ float rf[256], rf2[256];
    __shared__ unsigned int ru[256];
    const int b = blockIdx.y, seg = blockIdx.x, t = threadIdx.x;
    if (t < GG) sg[t] = gts[(size_t)b * GG + t];
    for (int j = t; j < NB / 2; j += 256) hp[j] = 0u;
    if (t < SEGA / 32) bmap[t] = 0u;
    __syncthreads();

    // fold force-match winners; mark ones landing in this segment
    {
        const int gg = t >> 3, p = t & 7;     // 256 threads = 32 gts x 8 chunks
        const unsigned long long* fp =
            &g_fpart[((size_t)b * GG + gg) * MBLK + p * 8];
        unsigned long long k = 0;
#pragma unroll
        for (int m = 0; m < 8; ++m) { const unsigned long long v = fp[m]; if (v > k) k = v; }
#pragma unroll
        for (int off = 1; off < 8; off <<= 1) {
            const unsigned long long o = __shfl_xor(k, off, 64);
            if (o > k) k = o;
        }
        if (p == 0) {
            const unsigned int a = 0xFFFFFFFFu - (unsigned int)(k & 0xFFFFFFFFull);
            const int la = (int)a - seg * SEGA;
            if (la >= 0 && la < SEGA) atomicOr(&bmap[la >> 5], 1u << (la & 31));
        }
    }
    __syncthreads();

    const size_t base = (size_t)b * AA + (size_t)seg * SEGA;   // anchor units
    const float4* c4 = (const float4*)(conf + base);
    const uchar4* m4 = (const uchar4*)(g_mask + base);
    const uchar4* x4 = (const uchar4*)(g_bidx + base);
    const float4* bb4 = bbox + base;

    float pos = 0.0f, loc = 0.0f;
    int np = 0;
#pragma unroll
    for (int j = 0; j < SEGA / 1024; ++j) {   // 4 iterations, 4 anchors/thread
        const int idx = j * 256 + t;
        const float4 p4 = c4[idx];
        const uchar4 mm = m4[idx];
        const uchar4 xx = x4[idx];
        const unsigned int bw = (bmap[idx >> 3] >> ((idx & 7) * 4)) & 0xFu;
        const float pv[4] = {p4.x, p4.y, p4.z, p4.w};
        const unsigned char mv[4] = {mm.x, mm.y, mm.z, mm.w};
        const unsigned char xv[4] = {xx.x, xx.y, xx.z, xx.w};
#pragma unroll
        for (int c = 0; c < 4; ++c) {
            const float p = pv[c];
            if (mv[c] | ((bw >> c) & 1u)) {
                np += 1;
                pos += -logf(p);
                const float4 bv = bb4[4 * idx + c];
                const float4 gb = sg[xv[c]];
                const float d0 = (bv.x + bv.z) * 0.5f - (gb.x + gb.z) * 0.5f;
                const float d1 = (bv.y + bv.w) * 0.5f - (gb.y + gb.w) * 0.5f;
                const float d2 = (bv.z - bv.x) - (gb.z - gb.x);
                const float d3 = (bv.w - bv.y) - (gb.w - gb.y);
                float ds[4] = {d0, d1, d2, d3};
#pragma unroll
                for (int q = 0; q < 4; ++q) {
                    float ax = fabsf(ds[q]);
                    loc += (ax < 1.0f) ? 0.5f * ax * ax : ax - 0.5f;
                }
            } else {
                const float nb = -log1pf(-p);
                int key = (int)(__float_as_uint(nb) >> 14) - (int)KOFF;
                key = key < 0 ? 0 : (key > NB - 1 ? NB - 1 : key);
                atomicAdd(&hp[key >> 1], 1u << ((key & 1) << 4));
            }
        }
    }
    // block reduce np/pos/loc (barriers also fence the LDS hist atomics)
    ru[t] = (unsigned int)np; rf[t] = pos; rf2[t] = loc;
    __syncthreads();
    for (int w = 128; w > 0; w >>= 1) {
        if (t < w) { ru[t] += ru[t + w]; rf[t] += rf[t + w]; rf2[t] += rf2[t + w]; }
        __syncthreads();
    }
    if (t == 0) {
        g_npart[b * NSEG + seg] = (int)ru[0];
        g_spart[(b * NSEG + seg) * 2 + 0] = rf[0];
        g_spart[(b * NSEG + seg) * 2 + 1] = rf2[0];
    }
    unsigned int* outp = g_hpart + ((size_t)b * NSEG + seg) * (NB / 2);
    for (int j = t; j < NB / 2; j += 256) outp[j] = hp[j];
}

// ---------------------------------------------------------------------------
// Kernel 3: per-image fold + hard-negative top-k + (last block) final combine.
// grid B, block 1024. Cross-block handoff: writer stores per-image results,
// __threadfence(), atomicAdd(g_done); the 16th block re-fences and reads all
// images' results with agent-scope atomic loads (XCD-coherence safe), then
// writes the dual-bf16-encoded output (R4/R5: exact match, keep).
__global__ void __launch_bounds__(1024) k_select(unsigned int* __restrict__ out) {
    __shared__ unsigned int hist[NB];         // 32 KB
    __shared__ unsigned int ru[1024];
    __shared__ unsigned int s2[32];
    __shared__ float sh_pos, sh_loc;
    __shared__ int sh_np, sh_k, sh_bsel;
    __shared__ unsigned int sh_take;
    __shared__ float rf[1024];

    const int b = blockIdx.x, t = threadIdx.x;
    // fold 16 packed partial hists -> u32 LDS hist
    for (int w = t; w < NB / 2; w += 1024) {
        unsigned int lo = 0, hi = 0;
#pragma unroll
        for (int s = 0; s < NSEG; ++s) {
            const unsigned int v = g_hpart[((size_t)b * NSEG + s) * (NB / 2) + w];
            lo += v & 0xFFFFu; hi += v >> 16;
        }
        hist[2 * w] = lo; hist[2 * w + 1] = hi;
    }
    if (t == 0) {
        int np = 0; float pos = 0.0f, loc = 0.0f;
        for (int s = 0; s < NSEG; ++s) {
            np += g_npart[b * NSEG + s];
            pos += g_spart[(b * NSEG + s) * 2 + 0];
            loc += g_spart[(b * NSEG + s) * 2 + 1];
        }
        sh_np = np; sh_pos = pos; sh_loc = loc;
    }
    __syncthreads();
    const int np_tot = sh_np;

    // descending chunk counts: thread t covers bins NB-1-8t .. NB-8-8t
    unsigned int c = 0;
    const int hi = NB - 1 - t * 8;
#pragma unroll
    for (int j = 0; j < 8; ++j) c += hist[hi - j];
    ru[t] = c;
    __syncthreads();
    if (t < 32) {
        unsigned int x = 0;
#pragma unroll
        for (int j = 0; j < 32; ++j) x += ru[t * 32 + j];
        s2[t] = x;
    }
    __syncthreads();
    if (t == 0) {
        int k = 3 * np_tot;
        const int maxneg = AA - np_tot;
        if (k > maxneg) k = maxneg;
        sh_k = k;
        int bsel = NB;            // NB => nothing selected
        unsigned int take = 0;
        if (k > 0) {
            unsigned int cum = 0;
            int u = 0;
            while (u < 31 && cum + s2[u] < (unsigned int)k) { cum += s2[u]; ++u; }
            int cc = u * 32;
            while (cc < 1023 && cum + ru[cc] < (unsigned int)k) { cum += ru[cc]; ++cc; }
            const int h2 = NB - 1 - cc * 8;
            int j = 0;
            while (j < 7 && cum + hist[h2 - j] < (unsigned int)k) { cum += hist[h2 - j]; ++j; }
            bsel = h2 - j;
            take = (unsigned int)k - cum;
        }
        sh_bsel = bsel; sh_take = take;
    }
    __syncthreads();
    const int bsel = sh_bsel;
    float negp = 0.0f;
    for (int j = t; j < NB; j += 1024)
        if (j > bsel) { unsigned int cnt = hist[j]; if (cnt) negp += (float)cnt * midval(j); }
    rf[t] = negp;
    __syncthreads();
    for (int w = 512; w > 0; w >>= 1) {
        if (t < w) rf[t] += rf[t + w];
        __syncthreads();
    }
    if (t == 0) {
        float neg = 0.0f;
        if (sh_k > 0) neg = rf[0] + (float)sh_take * midval(bsel < NB ? bsel : 0);
        g_loc[b] = sh_loc; g_pos[b] = sh_pos; g_neg[b] = neg;
        g_npos[b] = np_tot; g_nneg[b] = sh_k;

        __threadfence();                        // publish before counting in
        const int old = atomicAdd(&g_done, 1);
        if (old == BB - 1) {                    // last image: final combine
            __threadfence();
            float loc = 0.0f, conf = 0.0f;
            int tot = 0;
            for (int bb = 0; bb < BB; ++bb) {
                const float lv = __hip_atomic_load(&g_loc[bb],  __ATOMIC_RELAXED, __HIP_MEMORY_SCOPE_AGENT);
                const float pv = __hip_atomic_load(&g_pos[bb],  __ATOMIC_RELAXED, __HIP_MEMORY_SCOPE_AGENT);
                const float nv = __hip_atomic_load(&g_neg[bb],  __ATOMIC_RELAXED, __HIP_MEMORY_SCOPE_AGENT);
                const int   np = __hip_atomic_load(&g_npos[bb], __ATOMIC_RELAXED, __HIP_MEMORY_SCOPE_AGENT);
                const int   nn = __hip_atomic_load(&g_nneg[bb], __ATOMIC_RELAXED, __HIP_MEMORY_SCOPE_AGENT);
                loc += lv;
                conf += pv / (float)(np > 1 ? np : 1) +
                        nv / (float)(nn > 1 ? nn : 1);
                tot += np;
            }
            const float total = loc / (float)(tot > 1 ? tot : 1) + conf / (float)BB;
            const unsigned int u = __float_as_uint(total);
            const unsigned int r = 0x7FFFu + ((u >> 16) & 1u);
            const unsigned int bf = (u + r) >> 16;      // bf16(total), RNE
            out[0] = (bf << 16) | bf;
        }
    }
}

extern "C" void kernel_launch(void* const* d_in, const int* in_sizes, int n_in,
                              void* d_out, int out_size, void* d_ws, size_t ws_size,
                              hipStream_t stream) {
    const float4* bbox    = (const float4*)d_in[0];
    const float*  conf    = (const float*)d_in[1];
    const float4* anchors = (const float4*)d_in[2];
    const float4* gts     = (const float4*)d_in[3];

    k_matchforce<<<dim3(MBLK, BB), 256, 0, stream>>>(anchors, gts);
    k_stats<<<dim3(NSEG, BB), 256, 0, stream>>>(bbox, conf, gts);
    k_select<<<BB, 1024, 0, stream>>>((unsigned int*)d_out);
}